// Round 6
// baseline (472.963 us; speedup 1.0000x reference)
//
#include <hip/hip_runtime.h>
#include <hip/hip_bf16.h>

typedef __bf16 bf16_t;
typedef __attribute__((ext_vector_type(8))) __bf16 bf16x8;
typedef __attribute__((ext_vector_type(4))) float f32x4;

#define MFMA(a, b, c) __builtin_amdgcn_mfma_f32_16x16x32_bf16(a, b, c, 0, 0, 0)

// Diagnostic sentinel (fp32 output): absmax ~= val identifies the guard.
__global__ void fill_sentinel(float* out, int n, float val) {
  int i = blockIdx.x * blockDim.x + threadIdx.x;
  if (i < n) out[i] = val;
}

// Weights fp32 W[h][d][kk] (3 matrices) -> Wt bf16 [m][(h*64+kk)][d]
__global__ void transpose_w(const float* __restrict__ Wq, const float* __restrict__ Wk,
                            const float* __restrict__ Wv, bf16_t* __restrict__ Wt) {
  int gid = blockIdx.x * blockDim.x + threadIdx.x;
  int e = gid * 8;
  int m = e >> 20;
  int rem = e & 1048575;
  int n = rem >> 10;               // h*64+kk
  int d0 = rem & 1023;
  const float* W = (m == 0) ? Wq : (m == 1) ? Wk : Wv;
  int h = n >> 6, kk = n & 63;
  union { bf16_t h8[8]; uint4 u; } tmp;
#pragma unroll
  for (int j = 0; j < 8; ++j)
    tmp.h8[j] = (bf16_t)W[((size_t)(h * 1024 + d0 + j)) * 64 + kk];
  *(uint4*)(Wt + e) = tmp.u;
}

__device__ inline bf16x8 ld8(const bf16_t* p) { return *(const bf16x8*)p; }
__device__ inline bf16x8 ld8(const float* p) {
  f32x4 a = *(const f32x4*)p;
  f32x4 b = *(const f32x4*)(p + 4);
  bf16x8 r;
  r[0] = (bf16_t)a[0]; r[1] = (bf16_t)a[1]; r[2] = (bf16_t)a[2]; r[3] = (bf16_t)a[3];
  r[4] = (bf16_t)b[0]; r[5] = (bf16_t)b[1]; r[6] = (bf16_t)b[2]; r[7] = (bf16_t)b[3];
  return r;
}

// C = A[M,K] * Bt[N,K]^T. MODE 0: bf16 [h][b][s][dk]; MODE 1: bf16 [h][b][dk][s];
// MODE 2: fp32 [M,N] + bias (the final output).
template <int MODE, typename TA>
__global__ void gemm_bt(const TA* __restrict__ A, const void* __restrict__ Bt_,
                        const float* __restrict__ bias, void* __restrict__ out_,
                        int M, int N, int K) {
  constexpr int PAD = 40;
  __shared__ bf16_t sA[128 * PAD];
  __shared__ bf16_t sB[128 * PAD];
  const int t = threadIdx.x;
  const int w = t >> 6, l = t & 63;
  const int lq = l >> 4, ll = l & 15;
  const int m0 = blockIdx.x * 128, n0 = blockIdx.y * 128;
  const int wr = (w >> 1) * 64, wc = (w & 1) * 64;
  f32x4 acc[4][4] = {};
  for (int k0 = 0; k0 < K; k0 += 32) {
    __syncthreads();
#pragma unroll
    for (int r = 0; r < 2; ++r) {
      int e = (r * 256 + t) * 8;
      int row = e >> 5, col = e & 31;
      *(bf16x8*)(sA + row * PAD + col) = ld8(A + (size_t)(m0 + row) * K + k0 + col);
      if (MODE == 2)
        *(bf16x8*)(sB + row * PAD + col) =
            ld8((const float*)Bt_ + (size_t)(n0 + row) * K + k0 + col);
      else
        *(bf16x8*)(sB + row * PAD + col) =
            ld8((const bf16_t*)Bt_ + (size_t)(n0 + row) * K + k0 + col);
    }
    __syncthreads();
    bf16x8 af[4], bfr[4];
#pragma unroll
    for (int i = 0; i < 4; ++i) {
      af[i]  = *(const bf16x8*)(sA + (wr + i * 16 + ll) * PAD + lq * 8);
      bfr[i] = *(const bf16x8*)(sB + (wc + i * 16 + ll) * PAD + lq * 8);
    }
#pragma unroll
    for (int mi = 0; mi < 4; ++mi)
#pragma unroll
      for (int ni = 0; ni < 4; ++ni)
        acc[mi][ni] = MFMA(af[mi], bfr[ni], acc[mi][ni]);
  }
  // D layout: col=lane&15, row=(lane>>4)*4+reg (measured m89/m91).
#pragma unroll
  for (int mi = 0; mi < 4; ++mi)
#pragma unroll
    for (int ni = 0; ni < 4; ++ni)
#pragma unroll
      for (int r = 0; r < 4; ++r) {
        int row = m0 + wr + mi * 16 + lq * 4 + r;
        int col = n0 + wc + ni * 16 + ll;
        float v = acc[mi][ni][r];
        if (MODE == 2) {
          ((float*)out_)[(size_t)row * N + col] = v + bias[col];
        } else {
          int h = col >> 6, kk = col & 63, b = row >> 10, s = row & 1023;
          size_t idx;
          if (MODE == 0)
            idx = ((size_t)((h * 8 + b) * 1024 + s)) * 64 + kk;
          else
            idx = ((size_t)((h * 8 + b) * 64 + kk)) * 1024 + s;
          ((bf16_t*)out_)[idx] = (bf16_t)v;
        }
      }
}

// Flash attention. qh/kh: [h][b][s][dk], vt: [h][b][dk][s], c out: [b][s][h*64+dk].
// Block: 64 q-rows for one (h,b). 4 waves, each owns 16 q-rows.
// Value-verified against the scalar fp32 reference (rounds 2-5 agree to ~0.002).
__global__ void attn_kernel(const bf16_t* __restrict__ qh, const bf16_t* __restrict__ kh,
                            const bf16_t* __restrict__ vt, bf16_t* __restrict__ c) {
  constexpr int QP = 72, KP = 72, VP = 136, PP = 136;
  __shared__ bf16_t sQ[64 * QP];
  __shared__ bf16_t sK[128 * KP];
  __shared__ bf16_t sV[64 * VP];
  __shared__ bf16_t sP[4][16 * PP];
  const int t = threadIdx.x;
  const int w = t >> 6, l = t & 63;
  const int lq = l >> 4, ll = l & 15;
  const int q0 = blockIdx.x * 64;
  const int hb = blockIdx.y;          // h*8+b
  const int h = hb >> 3, b = hb & 7;
  const size_t base = (size_t)hb * 65536;
  const bf16_t* Q = qh + base + (size_t)q0 * 64;
  const bf16_t* K = kh + base;
  const bf16_t* V = vt + base;        // [64][1024]
#pragma unroll
  for (int r = 0; r < 2; ++r) {
    int e = (r * 256 + t) * 8;
    int row = e >> 6, col = e & 63;
    *(uint4*)(sQ + row * QP + col) = *(const uint4*)(Q + e);
  }
  float mrow[4], lrow[4];
  f32x4 o[4] = {};
#pragma unroll
  for (int r = 0; r < 4; ++r) { mrow[r] = -1e30f; lrow[r] = 0.f; }

  for (int kt = 0; kt < 1024; kt += 128) {
    __syncthreads();
#pragma unroll
    for (int r = 0; r < 4; ++r) {
      int e = (r * 256 + t) * 8;
      int row = e >> 6, col = e & 63;
      *(uint4*)(sK + row * KP + col) = *(const uint4*)(K + (size_t)kt * 64 + e);
      int rowv = e >> 7, colv = e & 127;
      *(uint4*)(sV + rowv * VP + colv) =
          *(const uint4*)(V + (size_t)rowv * 1024 + kt + colv);
    }
    __syncthreads();
    f32x4 sacc[8] = {};
    bf16x8 aq[2];
#pragma unroll
    for (int ks = 0; ks < 2; ++ks)
      aq[ks] = *(const bf16x8*)(sQ + (w * 16 + ll) * QP + ks * 32 + lq * 8);
#pragma unroll
    for (int ni = 0; ni < 8; ++ni)
#pragma unroll
      for (int ks = 0; ks < 2; ++ks) {
        bf16x8 bk = *(const bf16x8*)(sK + (ni * 16 + ll) * KP + ks * 32 + lq * 8);
        sacc[ni] = MFMA(aq[ks], bk, sacc[ni]);
      }
    float rmax[4] = {-1e30f, -1e30f, -1e30f, -1e30f};
#pragma unroll
    for (int ni = 0; ni < 8; ++ni)
#pragma unroll
      for (int r = 0; r < 4; ++r) {
        sacc[ni][r] *= 0.125f;
        rmax[r] = fmaxf(rmax[r], sacc[ni][r]);
      }
#pragma unroll
    for (int off = 1; off < 16; off <<= 1)
#pragma unroll
      for (int r = 0; r < 4; ++r)
        rmax[r] = fmaxf(rmax[r], __shfl_xor(rmax[r], off));
    float alpha[4];
#pragma unroll
    for (int r = 0; r < 4; ++r) {
      float mnew = fmaxf(mrow[r], rmax[r]);
      alpha[r] = __expf(mrow[r] - mnew);
      mrow[r] = mnew;
    }
    float rs[4] = {0.f, 0.f, 0.f, 0.f};
#pragma unroll
    for (int ni = 0; ni < 8; ++ni)
#pragma unroll
      for (int r = 0; r < 4; ++r) {
        float p = __expf(sacc[ni][r] - mrow[r]);
        sacc[ni][r] = p;
        rs[r] += p;
      }
#pragma unroll
    for (int off = 1; off < 16; off <<= 1)
#pragma unroll
      for (int r = 0; r < 4; ++r)
        rs[r] += __shfl_xor(rs[r], off);
#pragma unroll
    for (int r = 0; r < 4; ++r)
      lrow[r] = lrow[r] * alpha[r] + rs[r];
#pragma unroll
    for (int ni = 0; ni < 4; ++ni)
#pragma unroll
      for (int r = 0; r < 4; ++r)
        o[ni][r] *= alpha[r];
    bf16_t* Pw = sP[w];
#pragma unroll
    for (int ni = 0; ni < 8; ++ni)
#pragma unroll
      for (int r = 0; r < 4; ++r)
        Pw[(lq * 4 + r) * PP + ni * 16 + ll] = (bf16_t)sacc[ni][r];
    asm volatile("s_waitcnt lgkmcnt(0)" ::: "memory");
#pragma unroll
    for (int ks = 0; ks < 4; ++ks) {
      bf16x8 ap = *(const bf16x8*)(Pw + ll * PP + ks * 32 + lq * 8);
#pragma unroll
      for (int ni = 0; ni < 4; ++ni) {
        bf16x8 bv = *(const bf16x8*)(sV + (ni * 16 + ll) * VP + ks * 32 + lq * 8);
        o[ni] = MFMA(ap, bv, o[ni]);
      }
    }
  }
#pragma unroll
  for (int ni = 0; ni < 4; ++ni)
#pragma unroll
    for (int r = 0; r < 4; ++r) {
      int s = q0 + w * 16 + lq * 4 + r;
      int dk = ni * 16 + ll;
      float val = o[ni][r] / lrow[r];
      c[((size_t)(b * 1024 + s)) * 1024 + h * 64 + dk] = (bf16_t)val;
    }
}

extern "C" void kernel_launch(void* const* d_in, const int* in_sizes, int n_in,
                              void* d_out, int out_size, void* d_ws, size_t ws_size,
                              hipStream_t stream) {
  float* out = (float*)d_out;   // reference output dtype is fp32!
  int nblk_out = (out_size + 255) / 256;
  if (n_in != 8) {
    fill_sentinel<<<nblk_out, 256, 0, stream>>>(out, out_size, 600.0f + 10.0f * n_in);
    return;
  }
  const int expect[8] = {8388608, 8388608, 8388608, 1048576,
                         1048576, 1048576, 1048576, 1024};
  for (int i = 0; i < 8; ++i)
    if (in_sizes[i] != expect[i]) {
      fill_sentinel<<<nblk_out, 256, 0, stream>>>(out, out_size, 500.0f + 10.0f * i);
      return;
    }

  // ws map (bf16 elems): qh [0,8M) | kh [8M,16M) | vt [16M,24M) | Wt/cbuf [24M,32M)
  bf16_t* ws   = (bf16_t*)d_ws;
  bf16_t* qhb  = ws;
  bf16_t* khb  = ws + 8388608;
  bf16_t* vtb  = ws + 16777216;
  bf16_t* Wt   = ws + 25165824;
  bf16_t* cbuf = ws + 25165824;   // overlaps Wt (dead after projections)
  if (ws_size < 67108864ull) {
    fill_sentinel<<<nblk_out, 256, 0, stream>>>(out, out_size, 400.0f);
    return;
  }

  const float* q  = (const float*)d_in[0];
  const float* k  = (const float*)d_in[1];
  const float* v  = (const float*)d_in[2];
  const float* Wq = (const float*)d_in[3];
  const float* Wk = (const float*)d_in[4];
  const float* Wv = (const float*)d_in[5];
  const float* Wo = (const float*)d_in[6];
  const float* bo = (const float*)d_in[7];

  transpose_w<<<1536, 256, 0, stream>>>(Wq, Wk, Wv, Wt);
  dim3 gg(64, 8);
  gemm_bt<0, float><<<gg, 256, 0, stream>>>(q, Wt,           nullptr, qhb, 8192, 1024, 1024);
  gemm_bt<0, float><<<gg, 256, 0, stream>>>(k, Wt + 1048576, nullptr, khb, 8192, 1024, 1024);
  gemm_bt<1, float><<<gg, 256, 0, stream>>>(v, Wt + 2097152, nullptr, vtb, 8192, 1024, 1024);
  attn_kernel<<<dim3(16, 128), 256, 0, stream>>>(qhb, khb, vtb, cbuf);
  gemm_bt<2, bf16_t><<<gg, 256, 0, stream>>>(cbuf, Wo, bo, out, 8192, 1024, 1024);
}